// Round 9
// baseline (64.578 us; speedup 1.0000x reference)
//
#include <hip/hip_runtime.h>
#include <hip/hip_bf16.h>
#include <math.h>

#define Bn 128
#define Tn 512
#define Cn 256
#define Hn 64
#define NQKV 192
#define HP2 72          // padded bf16 LDS stride for attn tiles (144 B)
#define SCL 0.18033688011112042f   // log2(e)/8 : exp2-domain softmax scale

typedef __attribute__((ext_vector_type(8))) short short8v;   // 8 bf16
typedef __attribute__((ext_vector_type(4))) float float4v;   // MFMA C/D

__device__ __forceinline__ ushort f2bf(float f) {
    __hip_bfloat16 h = __float2bfloat16(f);   // RNE
    return *reinterpret_cast<ushort*>(&h);
}

// ---------------------------------------------------------------------------
// Prep: WcT[col][c] = W_m[c][h] as bf16 (plain row-major [col][k]).
// ---------------------------------------------------------------------------
__global__ __launch_bounds__(256) void prep_w_kernel(
    const float* __restrict__ Wq, const float* __restrict__ Wk,
    const float* __restrict__ Wv, ushort* __restrict__ wcT)
{
    const int col = blockIdx.x;          // 0..191
    const int c   = threadIdx.x;         // 0..255
    const float* W = (col < 64) ? Wq : (col < 128) ? Wk : Wv;
    const int h = col & 63;
    wcT[col * Cn + c] = f2bf(W[c * Hn + h]);
}

// ---------------------------------------------------------------------------
// QKV GEMM v5: many small blocks. 2048 blocks x 256 thr (4 waves),
// launch_bounds(256,4) -> 4 blocks/CU, ~21 KB LDS. 32-row tile, full N=192.
// Staging is tiny (8 float4/thread, freed before MFMA); W fragments read
// from L2 inside the unrolled loop (12 in flight, VGPR budget 128 allows
// it); q/k/vT all stored via LDS bounce as coalesced uint4 (1/thread each).
// Wave wv owns cols wv*48 (3 n-frags) x both 16-row m-strips.
// ---------------------------------------------------------------------------
__global__ __launch_bounds__(256, 4) void qkv_mfma_kernel(
    const float* __restrict__ x, const ushort* __restrict__ wcT,
    ushort* __restrict__ q, ushort* __restrict__ k, ushort* __restrict__ vT)
{
    // region0 [0,16384): x tile 32x512B swizzled; reused as q/k bounce [32][132]
    // region1 [16384, 16384+4608): Vb bounce [64 h][36 t]
    __shared__ char lds[16384 + 4608];
    const int VBOFF = 16384;

    const int tid  = threadIdx.x;
    const int lane = tid & 63;
    const int wv   = tid >> 6;             // 0..3 : 48-col strip
    const int lr   = lane & 15;
    const int hi   = lane >> 4;
    const long rows0 = (long)blockIdx.x * 32;

    // ---- stage x tile: 8 float4/thread -> cvt -> swizzled ds_write ----
    {
        const float4* x4 = (const float4*)(x + rows0 * Cn);
        float4 xr[8];
        #pragma unroll
        for (int i = 0; i < 8; ++i) xr[i] = x4[tid + i * 256];
        #pragma unroll
        for (int i = 0; i < 8; ++i) {
            int idx = tid + i * 256;           // 0..2047 uint2 slots
            int r   = idx >> 6;                // 0..31
            int c4  = idx & 63;
            union { ushort u[4]; uint2 p; } pk;
            pk.u[0] = f2bf(xr[i].x); pk.u[1] = f2bf(xr[i].y);
            pk.u[2] = f2bf(xr[i].z); pk.u[3] = f2bf(xr[i].w);
            int off = (r * 512 + c4 * 8) ^ ((r & 7) << 4);
            *(uint2*)(lds + off) = pk.p;
        }
    }
    __syncthreads();

    // ---- MFMA: 2 m-strips x 3 n-frags; A from LDS, B from L2 ----
    float4v acc[2][3];
    #pragma unroll
    for (int s = 0; s < 2; ++s)
        #pragma unroll
        for (int n = 0; n < 3; ++n) acc[s][n] = (float4v){0.f, 0.f, 0.f, 0.f};

    const ushort* bbase = wcT + (long)(wv * 48 + lr) * Cn + hi * 8;
    #pragma unroll
    for (int ks = 0; ks < 8; ++ks) {
        const int kb  = ks * 64 + hi * 16;
        const int a0o = (lr * 512 + kb) ^ ((lr & 7) << 4);
        short8v a0 = *(const short8v*)(lds + a0o);
        short8v a1 = *(const short8v*)(lds + a0o + 16 * 512);   // (lr+16)&7 == lr&7
        #pragma unroll
        for (int n = 0; n < 3; ++n) {
            short8v b = *(const short8v*)(bbase + n * 16 * Cn + ks * 32);
            acc[0][n] = __builtin_amdgcn_mfma_f32_16x16x32_bf16(a0, b, acc[0][n], 0, 0, 0);
            acc[1][n] = __builtin_amdgcn_mfma_f32_16x16x32_bf16(a1, b, acc[1][n], 0, 0, 0);
        }
    }
    __syncthreads();   // x tile dead -> region0 becomes q/k bounce

    // ---- bounce writes: q/k -> [t][col] stride 132; V -> Vb[h][t] stride 36
    #pragma unroll
    for (int s = 0; s < 2; ++s) {
        const int tl = s * 16 + hi * 4;
        #pragma unroll
        for (int n = 0; n < 3; ++n) {
            int col = wv * 48 + n * 16 + lr;
            if (col < 128) {
                #pragma unroll
                for (int reg = 0; reg < 4; ++reg)
                    *(ushort*)(lds + ((tl + reg) * 132 + col) * 2) = f2bf(acc[s][n][reg]);
            } else {
                int h = col - 128;
                #pragma unroll
                for (int reg = 0; reg < 4; ++reg)
                    *(ushort*)(lds + VBOFF + (h * 36 + tl + reg) * 2) = f2bf(acc[s][n][reg]);
            }
        }
    }
    __syncthreads();

    // ---- coalesced global stores: 1 uint4/thread for each of q, k, vT ----
    {
        const int t  = tid >> 3;               // 0..31
        const int h8 = tid & 7;                // 0..7
        uint4 vq = *(const uint4*)(lds + (t * 132 + h8 * 8) * 2);
        *(uint4*)(q + (rows0 + t) * Hn + h8 * 8) = vq;
        uint4 vk = *(const uint4*)(lds + (t * 132 + 64 + h8 * 8) * 2);
        *(uint4*)(k + (rows0 + t) * Hn + h8 * 8) = vk;

        const int h  = tid >> 2;               // 0..63
        const int t8 = tid & 3;                // 0..3
        const int bb = (int)(rows0 >> 9);
        const int t0 = (int)(rows0 & 511);
        uint4 vv = *(const uint4*)(lds + VBOFF + (h * 36 + t8 * 8) * 2);
        *(uint4*)(vT + ((long)bb * Hn + h) * Tn + t0 + t8 * 8) = vv;
    }
}

// ---------------------------------------------------------------------------
// MFMA flash attention, 128-row Q tile, 8 waves (512 thr). Unchanged (r4).
// ---------------------------------------------------------------------------
__global__ __launch_bounds__(512) void attn_mfma_kernel(
    const ushort* __restrict__ q, const ushort* __restrict__ k,
    const ushort* __restrict__ vT, float* __restrict__ out)
{
    __shared__ ushort Ks[64 * HP2];        // [key s][h]
    __shared__ ushort Vt[64 * HP2];        // [h][key s]
    __shared__ ushort Pl[8][16 * HP2];     // per-wave P rows

    const int tid = threadIdx.x;
    const int f   = blockIdx.x;            // 0..511
    const int c   = f & 255;
    const int b   = c >> 1;
    const int par = c & 1;
    const int qtp = (f < 256) ? par : (3 - par);   // q-tile 0..3
    const int ntiles = 2 * qtp + 2;

    const long base  = (long)b * Tn * Hn;
    const int lane = tid & 63;
    const int wv   = tid >> 6;             // 0..7
    const int lr   = lane & 15;
    const int hi   = lane >> 4;

    const int qrow_g = qtp * 128 + wv * 16;
    const int mrow0  = qrow_g + hi * 4;

    short8v qa[2];
    {
        const ushort* qp = q + base + (long)(qrow_g + lr) * Hn + hi * 8;
        qa[0] = *(const short8v*)(qp);
        qa[1] = *(const short8v*)(qp + 32);
    }

    const int sr  = tid >> 3;
    const int sc8 = tid & 7;
    uint4 kreg = *(const uint4*)(k + base + (long)sr * Hn + sc8 * 8);
    uint4 vreg = *(const uint4*)(vT + base + (long)sr * Tn + sc8 * 8);

    float4v o[4];
    #pragma unroll
    for (int n = 0; n < 4; ++n) o[n] = (float4v){0.f, 0.f, 0.f, 0.f};
    float m[4], l[4];
    #pragma unroll
    for (int reg = 0; reg < 4; ++reg) { m[reg] = -INFINITY; l[reg] = 0.f; }

    for (int kt = 0; kt < ntiles; ++kt) {
        __syncthreads();
        *(uint4*)&Ks[sr * HP2 + sc8 * 8] = kreg;
        *(uint4*)&Vt[sr * HP2 + sc8 * 8] = vreg;
        __syncthreads();
        if (kt + 1 < ntiles) {
            kreg = *(const uint4*)(k  + base + (long)((kt + 1) * 64 + sr) * Hn + sc8 * 8);
            vreg = *(const uint4*)(vT + base + (long)sr * Tn + (kt + 1) * 64 + sc8 * 8);
        }
        if (kt * 64 > qrow_g + 15) continue;

        float4v s4[4];
        #pragma unroll
        for (int n = 0; n < 4; ++n) s4[n] = (float4v){0.f, 0.f, 0.f, 0.f};
        #pragma unroll
        for (int ks = 0; ks < 2; ++ks) {
            short8v a = qa[ks];
            #pragma unroll
            for (int n = 0; n < 4; ++n) {
                short8v bb = *(const short8v*)&Ks[(n * 16 + lr) * HP2 + ks * 32 + hi * 8];
                s4[n] = __builtin_amdgcn_mfma_f32_16x16x32_bf16(a, bb, s4[n], 0, 0, 0);
            }
        }

        const bool partial = (kt * 64 + 63 > qrow_g);
        if (partial) {
            #pragma unroll
            for (int n = 0; n < 4; ++n) {
                int kcol = kt * 64 + n * 16 + lr;
                #pragma unroll
                for (int reg = 0; reg < 4; ++reg) {
                    float y = s4[n][reg] * SCL;
                    s4[n][reg] = (kcol <= mrow0 + reg) ? y : -INFINITY;
                }
            }
        } else {
            #pragma unroll
            for (int n = 0; n < 4; ++n)
                #pragma unroll
                for (int reg = 0; reg < 4; ++reg) s4[n][reg] *= SCL;
        }

        #pragma unroll
        for (int reg = 0; reg < 4; ++reg) {
            float mx = fmaxf(fmaxf(s4[0][reg], s4[1][reg]),
                             fmaxf(s4[2][reg], s4[3][reg]));
            mx = fmaxf(mx, __shfl_xor(mx, 1));
            mx = fmaxf(mx, __shfl_xor(mx, 2));
            mx = fmaxf(mx, __shfl_xor(mx, 4));
            mx = fmaxf(mx, __shfl_xor(mx, 8));
            float mN = fmaxf(m[reg], mx);
            float sc = exp2f(m[reg] - mN);
            float ps = 0.f;
            #pragma unroll
            for (int n = 0; n < 4; ++n) {
                float p = exp2f(s4[n][reg] - mN);
                s4[n][reg] = p;
                ps += p;
            }
            ps += __shfl_xor(ps, 1);
            ps += __shfl_xor(ps, 2);
            ps += __shfl_xor(ps, 4);
            ps += __shfl_xor(ps, 8);
            l[reg] = l[reg] * sc + ps;
            m[reg] = mN;
            #pragma unroll
            for (int n = 0; n < 4; ++n) o[n][reg] *= sc;
        }

        #pragma unroll
        for (int n = 0; n < 4; ++n)
            #pragma unroll
            for (int reg = 0; reg < 4; ++reg)
                Pl[wv][(hi * 4 + reg) * HP2 + n * 16 + lr] = f2bf(s4[n][reg]);

        #pragma unroll
        for (int ks = 0; ks < 2; ++ks) {
            short8v a = *(const short8v*)&Pl[wv][lr * HP2 + ks * 32 + hi * 8];
            #pragma unroll
            for (int n = 0; n < 4; ++n) {
                short8v bb = *(const short8v*)&Vt[(n * 16 + lr) * HP2 + ks * 32 + hi * 8];
                o[n] = __builtin_amdgcn_mfma_f32_16x16x32_bf16(a, bb, o[n], 0, 0, 0);
            }
        }
    }

    #pragma unroll
    for (int reg = 0; reg < 4; ++reg) {
        float inv = 1.0f / l[reg];
        float* orow = out + base + (long)(mrow0 + reg) * Hn;
        #pragma unroll
        for (int n = 0; n < 4; ++n)
            orow[n * 16 + lr] = o[n][reg] * inv;
    }
}

extern "C" void kernel_launch(void* const* d_in, const int* in_sizes, int n_in,
                              void* d_out, int out_size, void* d_ws, size_t ws_size,
                              hipStream_t stream) {
    const float* x  = (const float*)d_in[0];
    const float* Wq = (const float*)d_in[1];
    const float* Wk = (const float*)d_in[2];
    const float* Wv = (const float*)d_in[3];
    float* out = (float*)d_out;

    const size_t n = (size_t)Bn * Tn * Hn;
    ushort* qws = (ushort*)d_ws;
    ushort* kws = qws + n;
    ushort* vTs = kws + n;
    ushort* wcT = vTs + n;      // W (bf16), 96 KB in d_ws

    prep_w_kernel<<<dim3(NQKV), 256, 0, stream>>>(Wq, Wk, Wv, wcT);
    qkv_mfma_kernel<<<dim3(Bn * Tn / 32), 256, 0, stream>>>(x, wcT, qws, kws, vTs);
    attn_mfma_kernel<<<dim3(512), 512, 0, stream>>>(qws, kws, vTs, out);
}

// Round 10
// 60.984 us; speedup vs baseline: 1.0589x; 1.0589x over previous
//
#include <hip/hip_runtime.h>
#include <hip/hip_bf16.h>
#include <math.h>

#define Bn 128
#define Tn 512
#define Cn 256
#define Hn 64
#define NQKV 192        // 3*H fused output columns
#define XP 264          // padded bf16 LDS stride for GEMM tiles
#define HP2 72          // padded bf16 LDS stride for attn tiles (144 B)
#define SCL 0.18033688011112042f   // log2(e)/8 : exp2-domain softmax scale

typedef __attribute__((ext_vector_type(8))) short short8v;   // 8 bf16
typedef __attribute__((ext_vector_type(4))) float float4v;   // MFMA C/D

__device__ __forceinline__ ushort f2bf(float f) {
    __hip_bfloat16 h = __float2bfloat16(f);   // RNE
    return *reinterpret_cast<ushort*>(&h);
}
__device__ __forceinline__ unsigned int bfpair(float lo, float hi) {
    return (unsigned int)f2bf(lo) | ((unsigned int)f2bf(hi) << 16);
}
__device__ __forceinline__ short8v pk8(float4 a, float4 b) {
    short8v r;
    r[0] = (short)f2bf(a.x); r[1] = (short)f2bf(a.y);
    r[2] = (short)f2bf(a.z); r[3] = (short)f2bf(a.w);
    r[4] = (short)f2bf(b.x); r[5] = (short)f2bf(b.y);
    r[6] = (short)f2bf(b.z); r[7] = (short)f2bf(b.w);
    return r;
}

// ---------------------------------------------------------------------------
// Prep: WcT[m*64+h][c] = W_m[c][h] as bf16 (row-major [col][k]).
// ---------------------------------------------------------------------------
__global__ __launch_bounds__(256) void prep_w_kernel(
    const float* __restrict__ Wq, const float* __restrict__ Wk,
    const float* __restrict__ Wv, ushort* __restrict__ wcT)
{
    const int row = blockIdx.x;          // 0..191
    const int c   = threadIdx.x;         // 0..255
    const float* W = (row < 64) ? Wq : (row < 128) ? Wk : Wv;
    const int h = row & 63;
    wcT[row * Cn + c] = f2bf(W[c * Hn + h]);
}

// ---------------------------------------------------------------------------
// QKV GEMM — r2 resurrection. 1024 blocks x 256 thr (4 waves), 135 KB LDS,
// W + x staged ONCE per block, all-LDS inner loop (8 ks x 12 MFMA), no
// epilogue barrier, no VGPR cap. Stores: q,k fp32 scalar dwords (r2-exact);
// V as bf16 ushort4 (4 accumulator regs = 4 consecutive t at fixed h in the
// transposed [b][h][t] layout -> aligned 8 B stores, no bounce needed).
// ---------------------------------------------------------------------------
__global__ __launch_bounds__(256) void qkv_mfma_kernel(
    const float* __restrict__ x, const ushort* __restrict__ wcT,
    float* __restrict__ q, float* __restrict__ k, ushort* __restrict__ vT)
{
    __shared__ ushort xs[64 * XP];
    __shared__ ushort wsh[NQKV * XP];
    const int tid = threadIdx.x;
    const long row0 = (long)blockIdx.x * 64;

    // stage WcT: 192*256 bf16 = 6144 uint4, 24/thread, coalesced
    {
        const uint4* w16 = (const uint4*)wcT;
        #pragma unroll
        for (int i = 0; i < 24; ++i) {
            int idx = tid + i * 256;
            int r   = idx >> 5;
            int c8  = idx & 31;
            *(uint4*)&wsh[r * XP + c8 * 8] = w16[idx];
        }
    }
    // stage x tile 64x256 fp32 -> bf16: 4096 float4, 16/thread, coalesced
    {
        const float4* x4 = (const float4*)(x + row0 * Cn);
        #pragma unroll
        for (int i = 0; i < 16; ++i) {
            int idx = tid + i * 256;
            int r   = idx >> 6;
            int c4  = idx & 63;
            float4 f = x4[idx];
            union { ushort u[4]; uint2 p; } pk;
            pk.u[0] = f2bf(f.x); pk.u[1] = f2bf(f.y);
            pk.u[2] = f2bf(f.z); pk.u[3] = f2bf(f.w);
            *(uint2*)&xs[r * XP + c4 * 4] = pk.p;
        }
    }
    __syncthreads();

    const int lane = tid & 63;
    const int wv   = tid >> 6;
    const int lr   = lane & 15;
    const int hi   = lane >> 4;

    const ushort* arow = &xs[(wv * 16 + lr) * XP + hi * 8];
    const ushort* brow = &wsh[lr * XP + hi * 8];

    float4v acc[12];
    #pragma unroll
    for (int n = 0; n < 12; ++n) acc[n] = (float4v){0.f, 0.f, 0.f, 0.f};

    #pragma unroll
    for (int ks = 0; ks < 8; ++ks) {
        short8v a = *(const short8v*)(arow + ks * 32);
        #pragma unroll
        for (int n = 0; n < 12; ++n) {
            short8v b = *(const short8v*)(brow + (n * 16) * XP + ks * 32);
            acc[n] = __builtin_amdgcn_mfma_f32_16x16x32_bf16(a, b, acc[n], 0, 0, 0);
        }
    }

    // q,k: fp32 scalar dword stores (r2-exact)
    const long grow0 = row0 + wv * 16 + hi * 4;
    #pragma unroll
    for (int n = 0; n < 8; ++n) {
        int col = n * 16 + lr;
        float* outp = (col < 64) ? q : k;
        int hcol = col & 63;
        #pragma unroll
        for (int reg = 0; reg < 4; ++reg)
            outp[(grow0 + reg) * Hn + hcol] = acc[n][reg];
    }
    // V: transposed bf16, one ushort4 (8 B) store per n-frag
    {
        const int bb   = (int)(row0 >> 9);
        const int tloc = (int)(grow0 & 511);
        #pragma unroll
        for (int n = 8; n < 12; ++n) {
            int h = (n - 8) * 16 + lr;
            ushort4 pk;
            pk.x = f2bf(acc[n][0]); pk.y = f2bf(acc[n][1]);
            pk.z = f2bf(acc[n][2]); pk.w = f2bf(acc[n][3]);
            *(ushort4*)(vT + ((long)bb * Hn + h) * Tn + tloc) = pk;
        }
    }
}

// ---------------------------------------------------------------------------
// MFMA flash attention, 128-row Q tile, 8 waves (512 thr). r4 structure;
// q/k now fp32 (converted to bf16 during the existing staging), vT bf16
// path byte-identical to r4.
// ---------------------------------------------------------------------------
__global__ __launch_bounds__(512) void attn_mfma_kernel(
    const float* __restrict__ q32, const float* __restrict__ k32,
    const ushort* __restrict__ vT, float* __restrict__ out)
{
    __shared__ ushort Ks[64 * HP2];        // [key s][h]
    __shared__ ushort Vt[64 * HP2];        // [h][key s]
    __shared__ ushort Pl[8][16 * HP2];     // per-wave P rows

    const int tid = threadIdx.x;
    const int f   = blockIdx.x;            // 0..511
    const int c   = f & 255;
    const int b   = c >> 1;
    const int par = c & 1;
    const int qtp = (f < 256) ? par : (3 - par);   // q-tile 0..3
    const int ntiles = 2 * qtp + 2;

    const long base  = (long)b * Tn * Hn;
    const int lane = tid & 63;
    const int wv   = tid >> 6;             // 0..7
    const int lr   = lane & 15;
    const int hi   = lane >> 4;

    const int qrow_g = qtp * 128 + wv * 16;
    const int mrow0  = qrow_g + hi * 4;

    short8v qa[2];
    {
        const float* qp = q32 + base + (long)(qrow_g + lr) * Hn + hi * 8;
        float4 a0 = *(const float4*)(qp);
        float4 a1 = *(const float4*)(qp + 4);
        float4 a2 = *(const float4*)(qp + 32);
        float4 a3 = *(const float4*)(qp + 36);
        qa[0] = pk8(a0, a1);
        qa[1] = pk8(a2, a3);
    }

    const int sr  = tid >> 3;
    const int sc8 = tid & 7;
    float4 kf0 = *(const float4*)(k32 + base + (long)sr * Hn + sc8 * 8);
    float4 kf1 = *(const float4*)(k32 + base + (long)sr * Hn + sc8 * 8 + 4);
    uint4 vreg = *(const uint4*)(vT + base + (long)sr * Tn + sc8 * 8);

    float4v o[4];
    #pragma unroll
    for (int n = 0; n < 4; ++n) o[n] = (float4v){0.f, 0.f, 0.f, 0.f};
    float m[4], l[4];
    #pragma unroll
    for (int reg = 0; reg < 4; ++reg) { m[reg] = -INFINITY; l[reg] = 0.f; }

    for (int kt = 0; kt < ntiles; ++kt) {
        __syncthreads();
        {
            uint4 kp;
            kp.x = bfpair(kf0.x, kf0.y); kp.y = bfpair(kf0.z, kf0.w);
            kp.z = bfpair(kf1.x, kf1.y); kp.w = bfpair(kf1.z, kf1.w);
            *(uint4*)&Ks[sr * HP2 + sc8 * 8] = kp;
            *(uint4*)&Vt[sr * HP2 + sc8 * 8] = vreg;
        }
        __syncthreads();
        if (kt + 1 < ntiles) {
            const float* kp2 = k32 + base + (long)((kt + 1) * 64 + sr) * Hn + sc8 * 8;
            kf0  = *(const float4*)(kp2);
            kf1  = *(const float4*)(kp2 + 4);
            vreg = *(const uint4*)(vT + base + (long)sr * Tn + (kt + 1) * 64 + sc8 * 8);
        }
        if (kt * 64 > qrow_g + 15) continue;

        float4v s4[4];
        #pragma unroll
        for (int n = 0; n < 4; ++n) s4[n] = (float4v){0.f, 0.f, 0.f, 0.f};
        #pragma unroll
        for (int ks = 0; ks < 2; ++ks) {
            short8v a = qa[ks];
            #pragma unroll
            for (int n = 0; n < 4; ++n) {
                short8v bb = *(const short8v*)&Ks[(n * 16 + lr) * HP2 + ks * 32 + hi * 8];
                s4[n] = __builtin_amdgcn_mfma_f32_16x16x32_bf16(a, bb, s4[n], 0, 0, 0);
            }
        }

        const bool partial = (kt * 64 + 63 > qrow_g);
        if (partial) {
            #pragma unroll
            for (int n = 0; n < 4; ++n) {
                int kcol = kt * 64 + n * 16 + lr;
                #pragma unroll
                for (int reg = 0; reg < 4; ++reg) {
                    float y = s4[n][reg] * SCL;
                    s4[n][reg] = (kcol <= mrow0 + reg) ? y : -INFINITY;
                }
            }
        } else {
            #pragma unroll
            for (int n = 0; n < 4; ++n)
                #pragma unroll
                for (int reg = 0; reg < 4; ++reg) s4[n][reg] *= SCL;
        }

        #pragma unroll
        for (int reg = 0; reg < 4; ++reg) {
            float mx = fmaxf(fmaxf(s4[0][reg], s4[1][reg]),
                             fmaxf(s4[2][reg], s4[3][reg]));
            mx = fmaxf(mx, __shfl_xor(mx, 1));
            mx = fmaxf(mx, __shfl_xor(mx, 2));
            mx = fmaxf(mx, __shfl_xor(mx, 4));
            mx = fmaxf(mx, __shfl_xor(mx, 8));
            float mN = fmaxf(m[reg], mx);
            float sc = exp2f(m[reg] - mN);
            float ps = 0.f;
            #pragma unroll
            for (int n = 0; n < 4; ++n) {
                float p = exp2f(s4[n][reg] - mN);
                s4[n][reg] = p;
                ps += p;
            }
            ps += __shfl_xor(ps, 1);
            ps += __shfl_xor(ps, 2);
            ps += __shfl_xor(ps, 4);
            ps += __shfl_xor(ps, 8);
            l[reg] = l[reg] * sc + ps;
            m[reg] = mN;
            #pragma unroll
            for (int n = 0; n < 4; ++n) o[n][reg] *= sc;
        }

        #pragma unroll
        for (int n = 0; n < 4; ++n)
            #pragma unroll
            for (int reg = 0; reg < 4; ++reg)
                Pl[wv][(hi * 4 + reg) * HP2 + n * 16 + lr] = f2bf(s4[n][reg]);

        #pragma unroll
        for (int ks = 0; ks < 2; ++ks) {
            short8v a = *(const short8v*)&Pl[wv][lr * HP2 + ks * 32 + hi * 8];
            #pragma unroll
            for (int n = 0; n < 4; ++n) {
                short8v bb = *(const short8v*)&Vt[(n * 16 + lr) * HP2 + ks * 32 + hi * 8];
                o[n] = __builtin_amdgcn_mfma_f32_16x16x32_bf16(a, bb, o[n], 0, 0, 0);
            }
        }
    }

    #pragma unroll
    for (int reg = 0; reg < 4; ++reg) {
        float inv = 1.0f / l[reg];
        float* orow = out + base + (long)(mrow0 + reg) * Hn;
        #pragma unroll
        for (int n = 0; n < 4; ++n)
            orow[n * 16 + lr] = o[n][reg] * inv;
    }
}

extern "C" void kernel_launch(void* const* d_in, const int* in_sizes, int n_in,
                              void* d_out, int out_size, void* d_ws, size_t ws_size,
                              hipStream_t stream) {
    const float* x  = (const float*)d_in[0];
    const float* Wq = (const float*)d_in[1];
    const float* Wk = (const float*)d_in[2];
    const float* Wv = (const float*)d_in[3];
    float* out = (float*)d_out;

    const size_t n = (size_t)Bn * Tn * Hn;   // 4.19M elements per tensor
    float*  qws = (float*)d_ws;              // fp32, 16.8 MB
    float*  kws = qws + n;                   // fp32, 16.8 MB
    ushort* vTs = (ushort*)(kws + n);        // bf16 [b][h][t], 8.4 MB
    ushort* wcT = vTs + n;                   // bf16 W, 96 KB

    prep_w_kernel<<<dim3(NQKV), 256, 0, stream>>>(Wq, Wk, Wv, wcT);
    qkv_mfma_kernel<<<dim3(Bn * Tn / 64), 256, 0, stream>>>(x, wcT, qws, kws, vTs);
    attn_mfma_kernel<<<dim3(512), 512, 0, stream>>>(qws, kws, vTs, out);
}